// Round 2
// baseline (39316.541 us; speedup 1.0000x reference)
//
#include <hip/hip_runtime.h>
#include <math.h>

namespace {
constexpr int WSZ = 7, HW = 49, CIN = 192, HEADS = 6, CH = 32, IMG = 224;
constexpr int KC = 16;                    // K-chunk for QKV GEMM
constexpr int NCHUNK = CIN / KC;          // 12
constexpr int NW = 96 * KC;               // 1536 weight elems / chunk
constexpr int NX = KC * HW;               // 784 x elems / chunk
constexpr int NSTG = NW + NX;             // 2320
constexpr int STG_IT = (NSTG + 255) / 256;// 10

__device__ __forceinline__ int grow(int r, int h) {
    // local qkv row r in [0,96) -> global w_qkv row (q rows 0..191, k 192.., v 384..)
    return (r < 32) ? (CH * h + r)
         : (r < 64) ? (CIN + CH * h + (r - 32))
                    : (2 * CIN + CH * h + (r - 64));
}

__global__ __launch_bounds__(256, 3)
void win_attn_v2(const float* __restrict__ x,
                 const float* __restrict__ w_qkv,
                 const float* __restrict__ b_qkv,
                 const float* __restrict__ w_dw,
                 const float* __restrict__ b_dw,
                 const float* __restrict__ w_proj,
                 const float* __restrict__ b_proj,
                 const float* __restrict__ temperature,
                 float* __restrict__ out)
{
    // 54232 B total -> 3 blocks/CU
    __shared__ __align__(16) float SW[2 * NW];       // 12288 B; reused as wpls[96][32] in G
    __shared__ __align__(16) float SX[2 * NX];       //  6272 B
    __shared__ __align__(16) float qh[96][HW];       // 18816 B  q:0-31 k:32-63 v:64-95
    __shared__ __align__(16) float attnb[HW][52];    // 10192 B  [n][m], pad 52
    __shared__ __align__(16) float un[1568];         //  6272 B  qTn[49][32] (D) / outb[32][49] (F,G)
    __shared__ float rnorm[2][HW];                   //   392 B  [0]=1/||q||, [1]=1/||k||

    const int tid  = threadIdx.x;
    const int lane = tid & 63;
    const int wv   = __builtin_amdgcn_readfirstlane(tid >> 6);

    // XCD swizzle: g&7 -> XCD (round-robin dispatch); wx fastest within an XCD
    const int g   = blockIdx.x;
    const int xcd = g & 7, u = g >> 3;
    const int b   = u >> 7, r7 = u & 127;
    const int hy  = xcd * 4 + (r7 >> 5), wx = r7 & 31;
    const int row0 = hy * WSZ, col0 = wx * WSZ;

    const int  p   = lane;
    const bool act = (lane < HW);
    const int  pS  = act ? p : 0;          // clamped pixel for unguarded LDS reads
    const int  py  = p / WSZ, px = p % WSZ;

    // pipelined global->reg loaders for one (w,x) K-chunk
    auto stage_load = [&](int kcS, float* tr, int h) {
        #pragma unroll
        for (int it = 0; it < STG_IT; ++it) {
            int idx = tid + 256 * it;
            float v = 0.f;
            if (idx < NW) {
                int r = idx >> 4, c = idx & 15;
                v = w_qkv[grow(r, h) * CIN + kcS * KC + c];
            } else if (idx < NSTG) {
                int j = idx - NW, c = j / HW, pp = j - c * HW;
                v = x[((b * CIN + kcS * KC + c) * IMG + row0 + pp / WSZ) * IMG
                      + col0 + pp % WSZ];
            }
            tr[it] = v;
        }
    };
    auto stage_write = [&](int buf, const float* tr) {
        #pragma unroll
        for (int it = 0; it < STG_IT; ++it) {
            int idx = tid + 256 * it;
            if (idx < NW)        SW[buf * NW + idx]        = tr[it];
            else if (idx < NSTG) SX[buf * NX + (idx - NW)] = tr[it];
        }
    };

    float pacc[48];                         // proj accum: oc = 96*ph + 24*wv + j
    #pragma unroll
    for (int j = 0; j < 48; ++j) pacc[j] = 0.f;

    for (int h = 0; h < HEADS; ++h) {
        // ---------- Phase A: QKV GEMM, double-buffered 16-ch chunks ----------
        {
            float tr[STG_IT];
            stage_load(0, tr, h);
            stage_write(0, tr);
        }
        __syncthreads();

        float acc[24];
        #pragma unroll
        for (int j = 0; j < 24; ++j) acc[j] = 0.f;

        for (int kc = 0; kc < NCHUNK; ++kc) {
            float trn[STG_IT];
            if (kc + 1 < NCHUNK) stage_load(kc + 1, trn, h);   // loads in flight

            const float* wb = SW + (kc & 1) * NW;
            const float* xb = SX + (kc & 1) * NX;
            #pragma unroll
            for (int cg = 0; cg < 4; ++cg) {
                float x0 = xb[(4 * cg + 0) * HW + pS];
                float x1 = xb[(4 * cg + 1) * HW + pS];
                float x2 = xb[(4 * cg + 2) * HW + pS];
                float x3 = xb[(4 * cg + 3) * HW + pS];
                #pragma unroll
                for (int j = 0; j < 24; ++j) {
                    const float4 w4 = *(const float4*)(wb + (24 * wv + j) * KC + 4 * cg);
                    acc[j] = fmaf(w4.x, x0, fmaf(w4.y, x1,
                             fmaf(w4.z, x2, fmaf(w4.w, x3, acc[j]))));
                }
            }
            if (kc + 1 < NCHUNK) stage_write((kc + 1) & 1, trn);
            __syncthreads();
        }
        if (act) {
            #pragma unroll
            for (int j = 0; j < 24; ++j)
                qh[24 * wv + j][p] = acc[j] + b_qkv[grow(24 * wv + j, h)];
        }
        __syncthreads();

        // ---------- Phase B: depthwise 3x3 (zero-padded inside window) ----------
        float cv[24];
        if (act) {
            #pragma unroll
            for (int j = 0; j < 24; ++j) {
                const int r = 24 * wv + j, o = grow(r, h);
                float wd[9];
                #pragma unroll
                for (int t = 0; t < 9; ++t) wd[t] = w_dw[o * 9 + t];
                float s = b_dw[o];
                #pragma unroll
                for (int ky = 0; ky < 3; ++ky) {
                    int yy = py + ky - 1;
                    #pragma unroll
                    for (int kx = 0; kx < 3; ++kx) {
                        int xx = px + kx - 1;
                        bool ok = (yy >= 0) & (yy < WSZ) & (xx >= 0) & (xx < WSZ);
                        float vv = ok ? qh[r][yy * WSZ + xx] : 0.f;
                        s = fmaf(wd[ky * 3 + kx], vv, s);
                    }
                }
                cv[j] = s;
            }
        }
        __syncthreads();
        if (act) {
            #pragma unroll
            for (int j = 0; j < 24; ++j) qh[24 * wv + j][p] = cv[j];
        }
        __syncthreads();

        // ---------- Phase C: 1/norms, then qTn[m][cc] = q*rq*t ----------
        if (tid < 2 * HW) {
            const int sgn = (tid >= HW) ? 1 : 0;
            const int m = tid - sgn * HW;
            float sum = 0.f;
            #pragma unroll
            for (int cc = 0; cc < CH; ++cc) {
                float v = qh[sgn * CH + cc][m];
                sum = fmaf(v, v, sum);
            }
            rnorm[sgn][m] = 1.0f / fmaxf(sqrtf(sum), 1e-12f);
        }
        __syncthreads();
        const float tH = temperature[h];
        for (int i = tid; i < HW * CH; i += 256) {
            int m = i >> 5, cc = i & 31;
            un[i] = qh[cc][m] * rnorm[0][m] * tH;
        }
        __syncthreads();

        // ---------- Phase D: attn + fused softmax (lane = key n) ----------
        float kreg[CH];
        if (act) {
            const float rk = rnorm[1][p];
            #pragma unroll
            for (int cc = 0; cc < CH; ++cc) kreg[cc] = qh[CH + cc][p] * rk;
        }
        for (int m = wv; m < HW; m += 4) {
            const float4* qt = (const float4*)(un + m * CH);
            float s = 0.f;
            #pragma unroll
            for (int q4 = 0; q4 < 8; ++q4) {
                const float4 v4 = qt[q4];
                s = fmaf(kreg[4 * q4 + 0], v4.x, s);
                s = fmaf(kreg[4 * q4 + 1], v4.y, s);
                s = fmaf(kreg[4 * q4 + 2], v4.z, s);
                s = fmaf(kreg[4 * q4 + 3], v4.w, s);
            }
            float mx = act ? s : -3.4e38f;
            #pragma unroll
            for (int off = 32; off >= 1; off >>= 1)
                mx = fmaxf(mx, __shfl_xor(mx, off));
            float e = act ? __expf(s - mx) : 0.f;
            float sm = e;
            #pragma unroll
            for (int off = 32; off >= 1; off >>= 1)
                sm += __shfl_xor(sm, off);
            if (act) attnb[p][m] = e / sm;
        }
        __syncthreads();

        // ---------- Phase F: out[cc][m] = v @ attn, 2cc x 4m register tiles ----------
        {
            const int cct = tid / 13, mt = tid - 13 * cct;   // valid for tid < 208
            float f0[4] = {0.f, 0.f, 0.f, 0.f}, f1[4] = {0.f, 0.f, 0.f, 0.f};
            if (tid < 208) {
                const int m0 = 4 * mt;
                for (int n = 0; n < HW; ++n) {
                    const float va0 = qh[64 + 2 * cct + 0][n];
                    const float va1 = qh[64 + 2 * cct + 1][n];
                    const float4 a4 = *(const float4*)&attnb[n][m0];
                    f0[0] = fmaf(va0, a4.x, f0[0]); f0[1] = fmaf(va0, a4.y, f0[1]);
                    f0[2] = fmaf(va0, a4.z, f0[2]); f0[3] = fmaf(va0, a4.w, f0[3]);
                    f1[0] = fmaf(va1, a4.x, f1[0]); f1[1] = fmaf(va1, a4.y, f1[1]);
                    f1[2] = fmaf(va1, a4.z, f1[2]); f1[3] = fmaf(va1, a4.w, f1[3]);
                }
                #pragma unroll
                for (int k = 0; k < 4; ++k) {
                    if (m0 + k < HW) {
                        un[(2 * cct + 0) * HW + m0 + k] = f0[k];
                        un[(2 * cct + 1) * HW + m0 + k] = f1[k];
                    }
                }
            }
        }
        __syncthreads();

        // ---------- Phase G: proj partial, w_proj staged through SW ----------
        for (int ph = 0; ph < 2; ++ph) {
            for (int i = tid; i < 96 * CH; i += 256)
                SW[i] = w_proj[(96 * ph + (i >> 5)) * CIN + CH * h + (i & 31)];
            __syncthreads();
            if (act) {
                #pragma unroll
                for (int cg = 0; cg < 8; ++cg) {
                    const float o0 = un[(4 * cg + 0) * HW + p];
                    const float o1 = un[(4 * cg + 1) * HW + p];
                    const float o2 = un[(4 * cg + 2) * HW + p];
                    const float o3 = un[(4 * cg + 3) * HW + p];
                    #pragma unroll
                    for (int j = 0; j < 24; ++j) {
                        const float4 w4 = *(const float4*)&SW[(24 * wv + j) * CH + 4 * cg];
                        pacc[24 * ph + j] = fmaf(w4.x, o0, fmaf(w4.y, o1,
                                            fmaf(w4.z, o2, fmaf(w4.w, o3, pacc[24 * ph + j]))));
                    }
                }
            }
            __syncthreads();   // protect SW before next stage / next head's Phase A
        }
    }

    // ---------- epilogue: bias + window-reverse store ----------
    if (act) {
        #pragma unroll
        for (int ph = 0; ph < 2; ++ph)
            #pragma unroll
            for (int j = 0; j < 24; ++j) {
                const int oc = 96 * ph + 24 * wv + j;
                out[((b * CIN + oc) * IMG + row0 + py) * IMG + col0 + px] =
                    pacc[24 * ph + j] + b_proj[oc];
            }
    }
}
} // namespace

extern "C" void kernel_launch(void* const* d_in, const int* in_sizes, int n_in,
                              void* d_out, int out_size, void* d_ws, size_t ws_size,
                              hipStream_t stream) {
    const float* x      = (const float*)d_in[0];
    const float* w_qkv  = (const float*)d_in[1];
    const float* b_qkv  = (const float*)d_in[2];
    const float* w_dw   = (const float*)d_in[3];
    const float* b_dw   = (const float*)d_in[4];
    const float* w_proj = (const float*)d_in[5];
    const float* b_proj = (const float*)d_in[6];
    const float* temp   = (const float*)d_in[7];

    win_attn_v2<<<dim3(4096), dim3(256), 0, stream>>>(
        x, w_qkv, b_qkv, w_dw, b_dw, w_proj, b_proj, temp, (float*)d_out);
}